// Round 12
// baseline (138.752 us; speedup 1.0000x reference)
//
#include <hip/hip_runtime.h>

// SSIM (7x7 uniform window) over B=64, C=1, H=W=384 fp32 images.
// out = mean over interior 378x378 crop of all 64 images (scalar).
//
// R24 = R21 (best 129.3us: no-LDS direct-tap, 4-wave blocks, BAND 24,
// lb(256,3), fused div, float acc, branchless emit) + SHUFFLE-SHARED TAPS.
// R23 (pair-batched loads) was neutral -> the per-row-LATENCY family is
// falsified. Last untested resource: VMEM request / L1-tag throughput.
// Old dorow: 8 wave-wide loads/row, lanes stride 8B -> ~5 line-lookups per
// instr, ~40 lookups/row, and the wave re-fetches the SAME ~1KB of lines
// 4x (horizontal tap overlap) through one 32KB L1 shared by 12 waves.
// New: lane loads ONLY its own float2 (idx base+lane); neighbors' taps via
// __shfl_down(m,1..3); 2-value edge (idx 64,65 of the 66-float2 span) via
// one extra load + broadcast + cndmask patch for lanes 61-63. Bit-identical
// values to R21. Per row: VMEM instrs 8 -> 4, tag lookups ~40 -> ~8, L1
// return ~4KB -> ~1.2KB; +~40 shuffle/select ops (R20 proved added VALU is
// free under this regime).
//
// K1 max_kernel: max(gt) -> ws_max (monotone-encoded uint, atomicMax)
// K2 ssim_kernel: 768 x 4-wave blocks, shuffle-shared taps, no LDS
// K3 final_kernel: sum partials, divide, store d_out[0]
//
// BANNED (measured): pair-batched per-row loads (R23, neutral); 4-col/lane
// at <3 waves/SIMD supplied (R22, 44.5us); ring-free recompute-evict at
// same wave count (R20, +6us); cross-runtime-loop ping-pong banks (R19,
// 70MB scratch spill); LDS tap staging in ANY schedule (R12/R14/R15,
// ~43us); coop grid.sync fusion (R13, +192us); 12B global_load_lds (R10);
// launch_bounds cap BELOW live set (R4); per-block __threadfence finalize
// (R3/R5); divergent per-row emit branch (fixed R21).

#define PADW 3
#define BT 256            // threads per block = 4 waves; wave w owns one band
#define WPB 4             // waves per block
#define BAND 24           // output rows per wave
#define SROWS (BAND + 6)  // 30 swept rows = 4 x 7 + 2

constexpr int B_ = 64, H_ = 384, W_ = 384;
constexpr int W2 = W_ / 2;                                // row length in float2
constexpr int OUTD = W_ - 2 * PADW;                       // 378
constexpr int NBANDS = 16;                                // 16 x 24 = 384 >= 378
constexpr int NBGRP  = NBANDS / WPB;                      // 4 band-groups
constexpr int NTILES = 3;                                 // 3 x 126 cols = 378
constexpr int TOTAL_PART = NTILES * NBANDS * B_;          // 3072 partials
constexpr double NPIX = (double)B_ * OUTD * OUTD;         // 9,144,576

__device__ __forceinline__ unsigned enc_f(float f) {
    unsigned u = __float_as_uint(f);
    return (u & 0x80000000u) ? ~u : (u | 0x80000000u);
}
__device__ __forceinline__ float dec_f(unsigned e) {
    return __uint_as_float((e & 0x80000000u) ? (e & 0x7fffffffu) : ~e);
}

__device__ __forceinline__ float2 f2add(float2 a, float2 b) { return make_float2(a.x + b.x, a.y + b.y); }
__device__ __forceinline__ float2 f2sub(float2 a, float2 b) { return make_float2(a.x - b.x, a.y - b.y); }

__device__ __forceinline__ float2 shfld2(float2 v, int d) {
    return make_float2(__shfl_down(v.x, d), __shfl_down(v.y, d));
}
__device__ __forceinline__ float2 bcast2(float2 v, int l) {
    return make_float2(__shfl(v.x, l), __shfl(v.y, l));
}

__global__ void __launch_bounds__(256)
max_kernel(const float4* __restrict__ g4, unsigned* ws_max, int n4) {
    int tid = blockIdx.x * blockDim.x + threadIdx.x;
    int stride = gridDim.x * blockDim.x;
    float m = -3.402823466e38f;
    for (int i = tid; i < n4; i += stride) {
        float4 v = g4[i];
        m = fmaxf(m, fmaxf(fmaxf(v.x, v.y), fmaxf(v.z, v.w)));
    }
#pragma unroll
    for (int off = 32; off > 0; off >>= 1)
        m = fmaxf(m, __shfl_down(m, off));
    __shared__ float sm[4];
    if ((threadIdx.x & 63) == 0) sm[threadIdx.x >> 6] = m;
    __syncthreads();
    if (threadIdx.x == 0) {
        float mm = fmaxf(fmaxf(sm[0], sm[1]), fmaxf(sm[2], sm[3]));
        // no zero-init needed: 0xAA poison = enc(+3e-13), dominated by enc(max)
        atomicMax(ws_max, enc_f(mm));
    }
}

// 49^4-rescaled SSIM numerator/denominator products (scale cancels in the
// ratio; exactly the reference formula).
__device__ __forceinline__ void ssim_nd(float a, float b, float sxx, float syy, float sxy,
                                        float C1q, float C2q, float& num, float& den) {
    const float covn = 49.0f / 48.0f;
    float ab   = a * b;
    float num1 = fmaf(2.0f, ab, C1q);
    float txy  = fmaf(49.0f, sxy, -ab);
    float num2 = fmaf(2.0f * covn, txy, C2q);
    float b2   = b * b;
    float aabb = fmaf(a, a, b2);
    float den1 = aabb + C1q;
    float spq  = sxx + syy;
    float tv   = fmaf(49.0f, spq, -aabb);
    float den2 = fmaf(covn, tv, C2q);
    num = num1 * num2;
    den = den1 * den2;
}

__global__ void __launch_bounds__(BT, 3)
ssim_kernel(const float* __restrict__ gt, const float* __restrict__ pred,
            const unsigned* __restrict__ ws_max, double* __restrict__ ws_part) {
    const int t    = threadIdx.x;
    const int lane = t & 63;
    const int wave = t >> 6;               // 0..3
    const int tile = blockIdx.x;           // 0..2 column tiles (126 out cols)
    const int band = blockIdx.y * WPB + wave;   // 0..15, one band per wave
    const int b    = blockIdx.z;           // 0..63 images
    const int bid  = (b * NBANDS + band) * NTILES + tile;

    const float dr  = dec_f(*ws_max);
    const float c1  = 0.01f * dr, c2 = 0.03f * dr;
    const float C1q = c1 * c1 * 2401.0f;   // C1 * 49^2
    const float C2q = c2 * c2 * 2401.0f;   // C2 * 49^2

    const int  row0   = band * BAND;
    const bool active = (lane < 63);  // lane -> out cols tile*126+2*lane, +1

    // wave's tap span: float2 idx base..base+65 within each row (66 x 8B =
    // 528B; tile 2 ends at idx 191 = W2-1, in-row). Lane's own element is
    // idx base+lane; neighbors come from shuffles; idx 64/65 via edge load.
    const int base = tile * 63;

    const float* gimg = gt   + (size_t)b * H_ * W_;
    const float* pimg = pred + (size_t)b * H_ * W_;

    // vertical ring of horizontal 7-tap sums (2 columns packed in float2).
    float2 rx[7], ry[7], rxx[7], ryy[7], rxy[7];
#pragma unroll
    for (int j = 0; j < 7; ++j) {
        rx[j] = make_float2(0.f, 0.f); ry[j] = rx[j];
        rxx[j] = rx[j]; ryy[j] = rx[j]; rxy[j] = rx[j];
    }
    float2 vx = make_float2(0.f, 0.f), vy = vx, vxx = vx, vyy = vx, vxy = vx;
    float acc = 0.0f;   // per-thread sum <= 48; double only at partial store

    const int eidx = 64 + (lane & 1);      // edge element: idx 64 (even lanes)
                                           // / idx 65 (odd lanes)

    // one row of the sweep. Tap acquisition: 2 loads/array (own + edge),
    // d1..d3 via shfl_down with lane-61..63 edge patch. Values bit-identical
    // to the direct-load version (same memory words). Straight-line (R21).
    auto dorow = [&](int i, int slot) {
        const int ir = min(row0 + i, H_ - 1);        // clamped image row
        const float2* gr = (const float2*)(gimg + (size_t)ir * W_) + base;
        const float2* pr = (const float2*)(pimg + (size_t)ir * W_) + base;

        float2 mg = gr[lane], xg = gr[eidx];         // 2 VMEM (was 4)
        float2 mp = pr[lane], xp = pr[eidx];

        // neighbor taps via crossbar; edge values broadcast from lanes 0/1
        float2 g1 = shfld2(mg, 1), g2 = shfld2(mg, 2), g3 = shfld2(mg, 3);
        float2 p1 = shfld2(mp, 1), p2 = shfld2(mp, 2), p3 = shfld2(mp, 3);
        float2 gx0 = bcast2(xg, 0), gx1 = bcast2(xg, 1);
        float2 px0 = bcast2(xp, 0), px1 = bcast2(xp, 1);

        // patch lanes whose shfl_down crossed the wave edge:
        //   d1 = idx lane+1: invalid only for lane 63 -> x0
        //   d2 = idx lane+2: lane 62 -> x0, lane 63 -> x1
        //   d3 = idx lane+3: lane 61 -> x0, lane 62 -> x1, lane 63 -> x1
        //       (lane 63 is inactive; any finite value is fine)
        float2 d0 = mg;
        float2 d1 = (lane < 63) ? g1 : gx0;
        float2 d2 = (lane < 62) ? g2 : ((lane == 62) ? gx0 : gx1);
        float2 d3 = (lane < 61) ? g3 : ((lane == 61) ? gx0 : gx1);
        float2 e0 = mp;
        float2 e1 = (lane < 63) ? p1 : px0;
        float2 e2 = (lane < 62) ? p2 : ((lane == 62) ? px0 : px1);
        float2 e3 = (lane < 61) ? p3 : ((lane == 61) ? px0 : px1);

        float hx0 = d0.x + d0.y + d1.x + d1.y + d2.x + d2.y + d3.x;
        float hy0 = e0.x + e0.y + e1.x + e1.y + e2.x + e2.y + e3.x;
        float hxx0 = fmaf(d0.x, d0.x, fmaf(d0.y, d0.y, fmaf(d1.x, d1.x,
                     fmaf(d1.y, d1.y, fmaf(d2.x, d2.x, fmaf(d2.y, d2.y, d3.x * d3.x))))));
        float hyy0 = fmaf(e0.x, e0.x, fmaf(e0.y, e0.y, fmaf(e1.x, e1.x,
                     fmaf(e1.y, e1.y, fmaf(e2.x, e2.x, fmaf(e2.y, e2.y, e3.x * e3.x))))));
        float hxy0 = fmaf(d0.x, e0.x, fmaf(d0.y, e0.y, fmaf(d1.x, e1.x,
                     fmaf(d1.y, e1.y, fmaf(d2.x, e2.x, fmaf(d2.y, e2.y, d3.x * e3.x))))));

        // horizontal slide for the second column: -tap0 +tap7
        float2 h_x  = make_float2(hx0,  hx0  - d0.x        + d3.y);
        float2 h_y  = make_float2(hy0,  hy0  - e0.x        + e3.y);
        float2 h_xx = make_float2(hxx0, hxx0 - d0.x * d0.x + d3.y * d3.y);
        float2 h_yy = make_float2(hyy0, hyy0 - e0.x * e0.x + e3.y * e3.y);
        float2 h_xy = make_float2(hxy0, hxy0 - d0.x * e0.x + d3.y * e3.y);

        // vertical sliding window: evict slot (holds row i-7), insert row i
        vx  = f2add(vx,  f2sub(h_x,  rx[slot]));  rx[slot]  = h_x;
        vy  = f2add(vy,  f2sub(h_y,  ry[slot]));  ry[slot]  = h_y;
        vxx = f2add(vxx, f2sub(h_xx, rxx[slot])); rxx[slot] = h_xx;
        vyy = f2add(vyy, f2sub(h_yy, ryy[slot])); ryy[slot] = h_yy;
        vxy = f2add(vxy, f2sub(h_xy, rxy[slot])); rxy[slot] = h_xy;

        if (i >= 6) {   // compile-time: rows 0..5 emit nothing at all
            const int orow = row0 + i - 6;
            float na, da, nb, db;
            ssim_nd(vx.x, vy.x, vxx.x, vyy.x, vxy.x, C1q, C2q, na, da);
            ssim_nd(vx.y, vy.y, vxx.y, vyy.y, vxy.y, C1q, C2q, nb, db);
            float val = fmaf(na, db, nb * da) / (da * db);
            bool keep = active && (orow < OUTD);   // v_cndmask, no branch
            acc += keep ? val : 0.0f;
        }
    };

    // sweep 30 rows: 4 groups x 7 (ring slot = j, compile-time) + 2-row tail
    // (slots 28%7=0, 29%7=1, compile-time). Rule #20 holds throughout.
#pragma unroll 1
    for (int g = 0; g < 4; ++g) {
#pragma unroll
        for (int j = 0; j < 7; ++j) dorow(g * 7 + j, j);
    }
    dorow(28, 0);
    dorow(29, 1);

    // per-wave reduction (float) -> one double store per wave (no atomics)
#pragma unroll
    for (int off2 = 32; off2 > 0; off2 >>= 1)
        acc += __shfl_down(acc, off2);
    if (lane == 0) ws_part[bid] = (double)acc;
}

__global__ void __launch_bounds__(256)
final_kernel(const double* __restrict__ ws_part, float* __restrict__ out) {
    const int t = threadIdx.x;
    double s = 0.0;
    for (int i = t; i < TOTAL_PART; i += 256) s += ws_part[i];
#pragma unroll
    for (int off = 32; off > 0; off >>= 1)
        s += __shfl_down(s, off);
    __shared__ double sd[4];
    if ((t & 63) == 0) sd[t >> 6] = s;
    __syncthreads();
    if (t == 0) out[0] = (float)((sd[0] + sd[1] + sd[2] + sd[3]) / NPIX);
}

extern "C" void kernel_launch(void* const* d_in, const int* in_sizes, int n_in,
                              void* d_out, int out_size, void* d_ws, size_t ws_size,
                              hipStream_t stream) {
    const float* gt   = (const float*)d_in[0];
    const float* pred = (const float*)d_in[1];
    // d_in[2] is the uniform 1/49 window -> constant-folded into the kernel.
    float* out = (float*)d_out;

    unsigned* ws_max  = (unsigned*)d_ws;                   // offset 0 (4 B)
    double*   ws_part = (double*)((char*)d_ws + 64);       // 3072 doubles (~24 KB)

    // no memset: 0xAA poison is benign for atomicMax (enc-space +3e-13),
    // and ws_part is fully written by ssim_kernel before final_kernel reads.

    const int n4 = B_ * H_ * W_ / 4;  // 2,359,296 float4s
    max_kernel<<<1024, 256, 0, stream>>>((const float4*)gt, ws_max, n4);

    dim3 grid(NTILES, NBGRP, B_);     // col tiles x band-groups x images
    ssim_kernel<<<grid, BT, 0, stream>>>(gt, pred, ws_max, ws_part);

    final_kernel<<<1, 256, 0, stream>>>(ws_part, out);
}

// Round 13
// 132.460 us; speedup vs baseline: 1.0475x; 1.0475x over previous
//
#include <hip/hip_runtime.h>

// SSIM (7x7 uniform window) over B=64, C=1, H=W=384 fp32 images.
// out = mean over interior 378x378 crop of all 64 images (scalar).
//
// R25 = REVERT to R21 (best measured: 129.3us) as the final state.
// Complete hypothesis ledger (13 kernels, R12-R24) -- every axis falsified:
//   staging (LDS interleaved/single-drain/direct/DMA widths): ~43us all
//   occupancy 14->32% (1-5 waves/SIMD): neutral
//   register pressure 44-170 VGPR (AGPR-shuffle fix R17: -6us, then flat)
//   VALU content +-50% (R20 recompute-evict): neutral per-row
//   explicit ILP (R19 ping-pong: 70MB spill; R23 pair-batch: neutral)
//   branchless straight-lining (R21: -2us, kept)
//   wave-row count -33% (R22: regressed, occupancy coupling)
//   VMEM request rate 8->4/row via shuffles (R24: +9.5us, shuffles land ON
//     the dependency chain)
// => ssim ~37us is the structural floor of this 30-row serial sliding-window
// sweep (live-set-capped occupancy x unremovable per-row chain). Timed
// region at best: 83us harness poison fills (80-82% HBM peak, their own
// roofline) + 6us max (BW roofline) + ~37us ssim + 1.5us final + gaps.
//
// Kernel structure (R21): no-LDS direct-tap, 4-wave blocks, BAND 24,
// lb(256,3), 49^4-rescaled ssim_nd, fused divide, float acc, branchless
// emit via v_cndmask.
//
// K1 max_kernel: max(gt) -> ws_max (monotone-encoded uint, atomicMax)
// K2 ssim_kernel: 768 x 4-wave blocks, direct global taps, no LDS
// K3 final_kernel: sum partials, divide, store d_out[0]
//
// BANNED (measured): shuffle-shared taps (R24, +9.5us); pair-batched loads
// (R23, neutral); 4-col/lane at <3 waves/SIMD (R22, 44.5us); ring-free
// recompute-evict at same wave count (R20, +6us); cross-runtime-loop
// ping-pong banks (R19, 70MB spill); LDS tap staging in ANY schedule
// (R12/R14/R15, ~43us); coop grid.sync fusion (R13, +192us); 12B
// global_load_lds (R10); launch_bounds cap BELOW live set (R4); per-block
// __threadfence finalize (R3/R5); divergent per-row emit branch (fixed R21).

#define PADW 3
#define BT 256            // threads per block = 4 waves; wave w owns one band
#define WPB 4             // waves per block
#define BAND 24           // output rows per wave
#define SROWS (BAND + 6)  // 30 swept rows = 4 x 7 + 2

constexpr int B_ = 64, H_ = 384, W_ = 384;
constexpr int W2 = W_ / 2;                                // row length in float2
constexpr int OUTD = W_ - 2 * PADW;                       // 378
constexpr int NBANDS = 16;                                // 16 x 24 = 384 >= 378
constexpr int NBGRP  = NBANDS / WPB;                      // 4 band-groups
constexpr int NTILES = 3;                                 // 3 x 126 cols = 378
constexpr int TOTAL_PART = NTILES * NBANDS * B_;          // 3072 partials
constexpr double NPIX = (double)B_ * OUTD * OUTD;         // 9,144,576

__device__ __forceinline__ unsigned enc_f(float f) {
    unsigned u = __float_as_uint(f);
    return (u & 0x80000000u) ? ~u : (u | 0x80000000u);
}
__device__ __forceinline__ float dec_f(unsigned e) {
    return __uint_as_float((e & 0x80000000u) ? (e & 0x7fffffffu) : ~e);
}

__device__ __forceinline__ float2 f2add(float2 a, float2 b) { return make_float2(a.x + b.x, a.y + b.y); }
__device__ __forceinline__ float2 f2sub(float2 a, float2 b) { return make_float2(a.x - b.x, a.y - b.y); }

__global__ void __launch_bounds__(256)
max_kernel(const float4* __restrict__ g4, unsigned* ws_max, int n4) {
    int tid = blockIdx.x * blockDim.x + threadIdx.x;
    int stride = gridDim.x * blockDim.x;
    float m = -3.402823466e38f;
    for (int i = tid; i < n4; i += stride) {
        float4 v = g4[i];
        m = fmaxf(m, fmaxf(fmaxf(v.x, v.y), fmaxf(v.z, v.w)));
    }
#pragma unroll
    for (int off = 32; off > 0; off >>= 1)
        m = fmaxf(m, __shfl_down(m, off));
    __shared__ float sm[4];
    if ((threadIdx.x & 63) == 0) sm[threadIdx.x >> 6] = m;
    __syncthreads();
    if (threadIdx.x == 0) {
        float mm = fmaxf(fmaxf(sm[0], sm[1]), fmaxf(sm[2], sm[3]));
        // no zero-init needed: 0xAA poison = enc(+3e-13), dominated by enc(max)
        atomicMax(ws_max, enc_f(mm));
    }
}

// 49^4-rescaled SSIM numerator/denominator products (scale cancels in the
// ratio; exactly the reference formula).
__device__ __forceinline__ void ssim_nd(float a, float b, float sxx, float syy, float sxy,
                                        float C1q, float C2q, float& num, float& den) {
    const float covn = 49.0f / 48.0f;
    float ab   = a * b;
    float num1 = fmaf(2.0f, ab, C1q);
    float txy  = fmaf(49.0f, sxy, -ab);
    float num2 = fmaf(2.0f * covn, txy, C2q);
    float b2   = b * b;
    float aabb = fmaf(a, a, b2);
    float den1 = aabb + C1q;
    float spq  = sxx + syy;
    float tv   = fmaf(49.0f, spq, -aabb);
    float den2 = fmaf(covn, tv, C2q);
    num = num1 * num2;
    den = den1 * den2;
}

__global__ void __launch_bounds__(BT, 3)
ssim_kernel(const float* __restrict__ gt, const float* __restrict__ pred,
            const unsigned* __restrict__ ws_max, double* __restrict__ ws_part) {
    const int t    = threadIdx.x;
    const int lane = t & 63;
    const int wave = t >> 6;               // 0..3
    const int tile = blockIdx.x;           // 0..2 column tiles (126 out cols)
    const int band = blockIdx.y * WPB + wave;   // 0..15, one band per wave
    const int b    = blockIdx.z;           // 0..63 images
    const int bid  = (b * NBANDS + band) * NTILES + tile;

    const float dr  = dec_f(*ws_max);
    const float c1  = 0.01f * dr, c2 = 0.03f * dr;
    const float C1q = c1 * c1 * 2401.0f;   // C1 * 49^2
    const float C2q = c2 * c2 * 2401.0f;   // C2 * 49^2

    const int  row0   = band * BAND;
    const bool active = (lane < 63);  // lane -> out cols tile*126+2*lane, +1

    // thread's tap base (float2 index in row): floats 2*tb .. 2*tb+7 cover
    // both columns' 7-tap windows. Clamp keeps lane 63 in-row on tile 2.
    const int tb = min(tile * 63 + lane, W2 - 4);

    const float2* gp = (const float2*)(gt   + (size_t)b * H_ * W_) + tb;
    const float2* pp = (const float2*)(pred + (size_t)b * H_ * W_) + tb;

    // vertical ring of horizontal 7-tap sums (2 columns packed in float2).
    // 5 x 7 x float2 = 70 VGPR live by design -- cap 170 fits it + headroom.
    float2 rx[7], ry[7], rxx[7], ryy[7], rxy[7];
#pragma unroll
    for (int j = 0; j < 7; ++j) {
        rx[j] = make_float2(0.f, 0.f); ry[j] = rx[j];
        rxx[j] = rx[j]; ryy[j] = rx[j]; rxy[j] = rx[j];
    }
    float2 vx = make_float2(0.f, 0.f), vy = vx, vxx = vx, vyy = vx, vxy = vx;
    float acc = 0.0f;   // per-thread sum <= 48; double only at partial store

    // one row of the sweep: loads taps, slides windows, emits output row i-6.
    // BRANCHLESS: no divergent if -- whole body is straight-line so the
    // scheduler can hoist the next rows' loads across it (R21 change).
    auto dorow = [&](int i, int slot) {
        const int ir = min(row0 + i, H_ - 1);        // clamped image row
        const float2* gr = gp + (size_t)ir * W2;
        const float2* pr = pp + (size_t)ir * W2;
        // 8 taps (4 float2) covering both columns' 7-tap windows
        float2 d0 = gr[0], d1 = gr[1], d2 = gr[2], d3 = gr[3];
        float2 e0 = pr[0], e1 = pr[1], e2 = pr[2], e3 = pr[3];

        float hx0 = d0.x + d0.y + d1.x + d1.y + d2.x + d2.y + d3.x;
        float hy0 = e0.x + e0.y + e1.x + e1.y + e2.x + e2.y + e3.x;
        float hxx0 = fmaf(d0.x, d0.x, fmaf(d0.y, d0.y, fmaf(d1.x, d1.x,
                     fmaf(d1.y, d1.y, fmaf(d2.x, d2.x, fmaf(d2.y, d2.y, d3.x * d3.x))))));
        float hyy0 = fmaf(e0.x, e0.x, fmaf(e0.y, e0.y, fmaf(e1.x, e1.x,
                     fmaf(e1.y, e1.y, fmaf(e2.x, e2.x, fmaf(e2.y, e2.y, e3.x * e3.x))))));
        float hxy0 = fmaf(d0.x, e0.x, fmaf(d0.y, e0.y, fmaf(d1.x, e1.x,
                     fmaf(d1.y, e1.y, fmaf(d2.x, e2.x, fmaf(d2.y, e2.y, d3.x * e3.x))))));

        // horizontal slide for the second column: -tap0 +tap7
        float2 h_x  = make_float2(hx0,  hx0  - d0.x        + d3.y);
        float2 h_y  = make_float2(hy0,  hy0  - e0.x        + e3.y);
        float2 h_xx = make_float2(hxx0, hxx0 - d0.x * d0.x + d3.y * d3.y);
        float2 h_yy = make_float2(hyy0, hyy0 - e0.x * e0.x + e3.y * e3.y);
        float2 h_xy = make_float2(hxy0, hxy0 - d0.x * e0.x + d3.y * e3.y);

        // vertical sliding window: evict slot (holds row i-7), insert row i
        vx  = f2add(vx,  f2sub(h_x,  rx[slot]));  rx[slot]  = h_x;
        vy  = f2add(vy,  f2sub(h_y,  ry[slot]));  ry[slot]  = h_y;
        vxx = f2add(vxx, f2sub(h_xx, rxx[slot])); rxx[slot] = h_xx;
        vyy = f2add(vyy, f2sub(h_yy, ryy[slot])); ryy[slot] = h_yy;
        vxy = f2add(vxy, f2sub(h_xy, rxy[slot])); rxy[slot] = h_xy;

        if (i >= 6) {   // compile-time: rows 0..5 emit nothing at all
            const int orow = row0 + i - 6;
            float na, da, nb, db;
            ssim_nd(vx.x, vy.x, vxx.x, vyy.x, vxy.x, C1q, C2q, na, da);
            ssim_nd(vx.y, vy.y, vxx.y, vyy.y, vxy.y, C1q, C2q, nb, db);
            // s1 + s2 = (na*db + nb*da) / (da*db): one divide per row.
            // All inputs finite (row-clamped image data; den >= C*q > 0),
            // so val is finite even for discarded lanes/rows.
            float val = fmaf(na, db, nb * da) / (da * db);
            bool keep = active && (orow < OUTD);   // v_cndmask, no branch
            acc += keep ? val : 0.0f;
        }
    };

    // sweep 30 rows: 4 groups x 7 (ring slot = j, compile-time) + 2-row tail
    // (slots 28%7=0, 29%7=1, compile-time). Rule #20 holds throughout.
#pragma unroll 1
    for (int g = 0; g < 4; ++g) {
#pragma unroll
        for (int j = 0; j < 7; ++j) dorow(g * 7 + j, j);
    }
    dorow(28, 0);
    dorow(29, 1);

    // per-wave reduction (float) -> one double store per wave (no atomics)
#pragma unroll
    for (int off2 = 32; off2 > 0; off2 >>= 1)
        acc += __shfl_down(acc, off2);
    if (lane == 0) ws_part[bid] = (double)acc;
}

__global__ void __launch_bounds__(256)
final_kernel(const double* __restrict__ ws_part, float* __restrict__ out) {
    const int t = threadIdx.x;
    double s = 0.0;
    for (int i = t; i < TOTAL_PART; i += 256) s += ws_part[i];
#pragma unroll
    for (int off = 32; off > 0; off >>= 1)
        s += __shfl_down(s, off);
    __shared__ double sd[4];
    if ((t & 63) == 0) sd[t >> 6] = s;
    __syncthreads();
    if (t == 0) out[0] = (float)((sd[0] + sd[1] + sd[2] + sd[3]) / NPIX);
}

extern "C" void kernel_launch(void* const* d_in, const int* in_sizes, int n_in,
                              void* d_out, int out_size, void* d_ws, size_t ws_size,
                              hipStream_t stream) {
    const float* gt   = (const float*)d_in[0];
    const float* pred = (const float*)d_in[1];
    // d_in[2] is the uniform 1/49 window -> constant-folded into the kernel.
    float* out = (float*)d_out;

    unsigned* ws_max  = (unsigned*)d_ws;                   // offset 0 (4 B)
    double*   ws_part = (double*)((char*)d_ws + 64);       // 3072 doubles (~24 KB)

    // no memset: 0xAA poison is benign for atomicMax (enc-space +3e-13),
    // and ws_part is fully written by ssim_kernel before final_kernel reads.

    const int n4 = B_ * H_ * W_ / 4;  // 2,359,296 float4s
    max_kernel<<<1024, 256, 0, stream>>>((const float4*)gt, ws_max, n4);

    dim3 grid(NTILES, NBGRP, B_);     // col tiles x band-groups x images
    ssim_kernel<<<grid, BT, 0, stream>>>(gt, pred, ws_max, ws_part);

    final_kernel<<<1, 256, 0, stream>>>(ws_part, out);
}